// Round 5
// baseline (343.047 us; speedup 1.0000x reference)
//
#include <hip/hip_runtime.h>
#include <math.h>

typedef unsigned long long u64;
typedef unsigned int u32;

#define NB 16
#define SL 1024
#define DIM 16
#define MDIM 16
#define KNN 8
#define EH 66    /* edge hidden */
#define EHP 68   /* padded to 4*17 */
#define CH 64    /* coors hidden */
#define NHID 32  /* node hidden */
#define LN_EPS 1e-5f
#define W1T_STRIDE 36

__device__ __forceinline__ float silu_f(float x) {
    return x / (1.0f + __expf(-x));
}

// ---------------- init ----------------
__global__ __launch_bounds__(256) void init_kernel(
    const float* __restrict__ coords, const int* __restrict__ residues,
    const float* __restrict__ token_emb, const float* __restrict__ pos_emb,
    float* __restrict__ coordsA, float* __restrict__ featsA)
{
    const int nid = blockIdx.x * 256 + threadIdx.x;
    if (nid >= NB * SL) return;
    const int l = nid & (SL - 1);
    const int r = residues[nid];
#pragma unroll
    for (int c = 0; c < DIM; ++c)
        featsA[nid * DIM + c] = token_emb[r * DIM + c] + pos_emb[l * DIM + c];
#pragma unroll
    for (int c = 0; c < 3; ++c)
        coordsA[nid * 3 + c] = coords[nid * 3 + c];
}

// ---------------- weight transpose/pack ----------------
__global__ __launch_bounds__(256) void pack_kernel(
    const float* __restrict__ ew1, const float* __restrict__ cw1,
    const float* __restrict__ nw1, const float* __restrict__ nw2,
    float* __restrict__ w1t, float* __restrict__ cw1t,
    float* __restrict__ nw1t, float* __restrict__ nw2t)
{
    const int stride = gridDim.x * 256;
    const int t0 = blockIdx.x * 256 + threadIdx.x;
    for (int idx = t0; idx < 3 * EH * 33; idx += stride) {
        int d = idx / (EH * 33); int r = idx - d * EH * 33; int u = r / 33; int c = r - u * 33;
        w1t[(d * EH + u) * W1T_STRIDE + c] = ew1[(d * 33 + c) * EH + u];
    }
    for (int idx = t0; idx < 3 * CH * 16; idx += stride) {
        int d = idx / (CH * 16); int r = idx - d * CH * 16; int t = r >> 4; int v = r & 15;
        cw1t[(d * CH + t) * 16 + v] = cw1[(d * 16 + v) * CH + t];
    }
    for (int idx = t0; idx < 3 * NHID * 32; idx += stride) {
        int d = idx / (NHID * 32); int r = idx - d * NHID * 32; int u = r >> 5; int c = r & 31;
        nw1t[(d * NHID + u) * 32 + c] = nw1[(d * 32 + c) * NHID + u];
    }
    for (int idx = t0; idx < 3 * 16 * 32; idx += stride) {
        int d = idx / (16 * 32); int r = idx - d * 16 * 32; int c = r >> 5; int u = r & 31;
        nw2t[(d * 16 + c) * 32 + u] = nw2[(d * 32 + u) * 16 + c];
    }
}

// ---------------- kNN: 32 queries/block, 32 slices of 32 candidates, 8 waves/SIMD ----------------
__device__ __forceinline__ void merge8(u32* a, const u32* bb) {
    u32 c[8];
#pragma unroll
    for (int t = 0; t < 8; ++t) c[t] = min(a[t], bb[7 - t]);
#define MCAS(x, y) { u32 mn = min(c[x], c[y]); u32 mx = max(c[x], c[y]); c[x] = mn; c[y] = mx; }
    MCAS(0, 4) MCAS(1, 5) MCAS(2, 6) MCAS(3, 7)
    MCAS(0, 2) MCAS(1, 3) MCAS(4, 6) MCAS(5, 7)
    MCAS(0, 1) MCAS(2, 3) MCAS(4, 5) MCAS(6, 7)
#undef MCAS
#pragma unroll
    for (int t = 0; t < 8; ++t) a[t] = c[t];
}

__global__ __launch_bounds__(1024) void knn_kernel(
    const float* __restrict__ coords, const int* __restrict__ lengths,
    int* __restrict__ idxbuf)
{
    __shared__ float s_cand[SL * 3];      // 12 KB
    __shared__ u32 lists[32][32][9];      // 36 KB
    const int tid = threadIdx.x;
    const int b = blockIdx.x >> 5;
    const int i0 = (blockIdx.x & 31) << 5;
    const int len = lengths[b];
    const float* cb = coords + (size_t)b * SL * 3;
    for (int idx = tid; idx < SL * 3; idx += 1024) s_cand[idx] = cb[idx];
    __syncthreads();

    const int wv = tid >> 6;
    const int lane = tid & 63;
    const int q = lane & 31;
    const int sub = lane >> 5;
    const int s = wv * 2 + sub;          // slice 0..31
    const int i = i0 + q;
    const float xi = s_cand[i * 3 + 0], yi = s_cand[i * 3 + 1], zi = s_cand[i * 3 + 2];

    u32 lst[8];
#pragma unroll
    for (int t = 0; t < 8; ++t) lst[t] = 0xFFFFFFFFu;

    const int jbase = s << 5;
#pragma unroll 4
    for (int jj = 0; jj < 32; ++jj) {
        const int j = jbase + jj;
        const float xj = s_cand[j * 3 + 0], yj = s_cand[j * 3 + 1], zj = s_cand[j * 3 + 2];
        const float dx = xi - xj, dy = yi - yj, dz = zi - zj;
        const float dist = dx * dx + dy * dy + dz * dz;
        const bool valid = j < len;
        // order-preserving pack; dist >= 0 so transform = |sign then truncate low 10 bits
        const u32 kd = (__float_as_uint(dist) | 0x80000000u) & 0xFFFFFC00u;
        u32 key = valid ? kd : 0xC7C35000u;           // key(1e5f)
        if (valid && (j == i + 1 || j + 1 == i)) key = 0x80000000u;   // key(0.0f): adjacency
        if (j == i) key = 0x407FFC00u;                 // key(-1.0f): self
        key |= (u32)j;
#pragma unroll
        for (int p = 7; p >= 1; --p)
            lst[p] = (key < lst[p]) ? ((key < lst[p - 1]) ? lst[p - 1] : key) : lst[p];
        lst[0] = min(key, lst[0]);
    }

#pragma unroll
    for (int t = 0; t < 8; ++t) lists[s][q][t] = lst[t];
    __syncthreads();

    if (tid < 512) {
        const int p = tid >> 5, qq = tid & 31;
        u32 a[8], bb[8];
#pragma unroll
        for (int t = 0; t < 8; ++t) { a[t] = lists[2 * p][qq][t]; bb[t] = lists[2 * p + 1][qq][t]; }
        merge8(a, bb);
#pragma unroll
        for (int t = 0; t < 8; ++t) lists[2 * p][qq][t] = a[t];
    }
    __syncthreads();
    if (tid < 256) {
        const int p = tid >> 5, qq = tid & 31;
        u32 a[8], bb[8];
#pragma unroll
        for (int t = 0; t < 8; ++t) { a[t] = lists[4 * p][qq][t]; bb[t] = lists[4 * p + 2][qq][t]; }
        merge8(a, bb);
#pragma unroll
        for (int t = 0; t < 8; ++t) lists[4 * p][qq][t] = a[t];
    }
    __syncthreads();
    if (tid < 128) {
        const int p = tid >> 5, qq = tid & 31;
        u32 a[8], bb[8];
#pragma unroll
        for (int t = 0; t < 8; ++t) { a[t] = lists[8 * p][qq][t]; bb[t] = lists[8 * p + 4][qq][t]; }
        merge8(a, bb);
#pragma unroll
        for (int t = 0; t < 8; ++t) lists[8 * p][qq][t] = a[t];
    }
    __syncthreads();
    if (tid < 64) {
        const int p = tid >> 5, qq = tid & 31;
        u32 a[8], bb[8];
#pragma unroll
        for (int t = 0; t < 8; ++t) { a[t] = lists[16 * p][qq][t]; bb[t] = lists[16 * p + 8][qq][t]; }
        merge8(a, bb);
#pragma unroll
        for (int t = 0; t < 8; ++t) lists[16 * p][qq][t] = a[t];
    }
    __syncthreads();
    if (tid < 32) {
        const int qq = tid;
        u32 a[8], bb[8];
#pragma unroll
        for (int t = 0; t < 8; ++t) { a[t] = lists[0][qq][t]; bb[t] = lists[16][qq][t]; }
        merge8(a, bb);
        const size_t node = (size_t)b * SL + i0 + qq;
        int4 r0 = make_int4((int)(a[0] & 1023u), (int)(a[1] & 1023u), (int)(a[2] & 1023u), (int)(a[3] & 1023u));
        int4 r1 = make_int4((int)(a[4] & 1023u), (int)(a[5] & 1023u), (int)(a[6] & 1023u), (int)(a[7] & 1023u));
        ((int4*)idxbuf)[node * 2 + 0] = r0;
        ((int4*)idxbuf)[node * 2 + 1] = r1;
    }
}

// ---------------- EGNN layer: 8 waves/block, 4-way wave split per 64-edge group,
// LDS-broadcast weights, wave specialization after combine ----------------
__global__ __launch_bounds__(512, 6) void layer_kernel(
    const int d,
    const float* __restrict__ coordsIn, float* __restrict__ coordsOut,
    const float* __restrict__ featsIn, float* __restrict__ featsOut,
    const int* __restrict__ idxbuf, const int* __restrict__ lengths,
    const float* __restrict__ w1t, const float* __restrict__ g_eb1,
    const float* __restrict__ g_ew2, const float* __restrict__ g_eb2,
    const float* __restrict__ cw1t, const float* __restrict__ g_cb1,
    const float* __restrict__ g_cw2, const float* __restrict__ g_cb2,
    const float* __restrict__ g_lng, const float* __restrict__ g_lnb,
    const float* __restrict__ nw1t, const float* __restrict__ g_nb1,
    const float* __restrict__ nw2t, const float* __restrict__ g_nb2)
{
    __shared__ float s_w1[EHP * 36];      // rows 66,67 zero
    __shared__ float s_w2e[EHP * 16];     // rows 66,67 zero
    __shared__ float s_cw1[CH * 16];
    __shared__ float s_cw2v[CH];
    __shared__ float s_nw1[NHID * 36];
    __shared__ float s_nw2[16 * 36];
    __shared__ float s_eb1[EHP], s_eb2[16], s_cb1[CH];
    __shared__ float s_lng[16], s_lnb[16], s_nb1[32], s_nb2[16];
    __shared__ float s_cb2v;
    __shared__ float s_bufA[2][16][66];   // exchange, transposed [v][lane]: coalesced, conflict-free
    __shared__ float s_bufB[2][16][66];
    __shared__ float s_wA[2][64], s_wB[2][64];

    const int tid = threadIdx.x;
    for (int t = tid; t < EHP * 36; t += 512) s_w1[t] = (t < EH * 36) ? w1t[d * EH * 36 + t] : 0.0f;
    for (int t = tid; t < EHP * 16; t += 512) s_w2e[t] = (t < EH * 16) ? g_ew2[d * EH * 16 + t] : 0.0f;
    for (int t = tid; t < CH * 16; t += 512) s_cw1[t] = cw1t[d * CH * 16 + t];
    for (int t = tid; t < NHID * 32; t += 512) s_nw1[(t >> 5) * 36 + (t & 31)] = nw1t[d * NHID * 32 + t];
    for (int t = tid; t < 16 * 32; t += 512) s_nw2[(t >> 5) * 36 + (t & 31)] = nw2t[d * 16 * 32 + t];
    if (tid < CH) { s_cw2v[tid] = g_cw2[d * CH + tid]; s_cb1[tid] = g_cb1[d * CH + tid]; }
    if (tid < EHP) s_eb1[tid] = (tid < EH) ? g_eb1[d * EH + tid] : 0.0f;
    if (tid >= 128 && tid < 144) {
        const int c = tid - 128;
        s_eb2[c] = g_eb2[d * 16 + c];
        s_lng[c] = g_lng[d * 16 + c];
        s_lnb[c] = g_lnb[d * 16 + c];
        s_nb2[c] = g_nb2[d * 16 + c];
    }
    if (tid >= 160 && tid < 192) s_nb1[tid - 160] = g_nb1[d * 32 + (tid - 160)];
    if (tid == 200) s_cb2v = g_cb2[d];

    const int wv = tid >> 6;
    const int g = wv >> 2;           // edge group 0/1
    const int qt = wv & 3;           // quarter (wave-uniform)
    const int lane = tid & 63;
    const int e = blockIdx.x * 128 + g * 64 + lane;
    const int n = e >> 3;
    const int b = n >> 10;
    const int i = n & (SL - 1);
    const int k = lane & 7;
    const int len = lengths[b];
    const int j = idxbuf[e];
    const bool em = (i < len) && (j < len);

    // ---- inputs ----
    float fi[16], fj[16];
    {
        const float4* pp = (const float4*)(featsIn + (size_t)n * DIM);
        float4 a = pp[0], c2 = pp[1], c3 = pp[2], c4 = pp[3];
        fi[0]=a.x; fi[1]=a.y; fi[2]=a.z; fi[3]=a.w;
        fi[4]=c2.x; fi[5]=c2.y; fi[6]=c2.z; fi[7]=c2.w;
        fi[8]=c3.x; fi[9]=c3.y; fi[10]=c3.z; fi[11]=c3.w;
        fi[12]=c4.x; fi[13]=c4.y; fi[14]=c4.z; fi[15]=c4.w;
    }
    {
        const float4* pp = (const float4*)(featsIn + ((size_t)b * SL + j) * DIM);
        float4 a = pp[0], c2 = pp[1], c3 = pp[2], c4 = pp[3];
        fj[0]=a.x; fj[1]=a.y; fj[2]=a.z; fj[3]=a.w;
        fj[4]=c2.x; fj[5]=c2.y; fj[6]=c2.z; fj[7]=c2.w;
        fj[8]=c3.x; fj[9]=c3.y; fj[10]=c3.z; fj[11]=c3.w;
        fj[12]=c4.x; fj[13]=c4.y; fj[14]=c4.z; fj[15]=c4.w;
    }
    float ci[3], rel[3];
    {
        const float* cp = coordsIn + (size_t)n * 3;
        const float* cq = coordsIn + ((size_t)b * SL + j) * 3;
        ci[0] = cp[0]; ci[1] = cp[1]; ci[2] = cp[2];
        rel[0] = ci[0] - cq[0]; rel[1] = ci[1] - cq[1]; rel[2] = ci[2] - cq[2];
    }
    const float rd = fmaf(rel[0], rel[0], fmaf(rel[1], rel[1], rel[2] * rel[2]));

    __syncthreads();   // sync0: weights staged

    // ---- edge MLP quarter: units [qt*17, qt*17+17) (rows 66,67 are zero) ----
    const int ub = qt * 17;
    float macc[16];
#pragma unroll
    for (int v = 0; v < 16; ++v) macc[v] = (qt == 0) ? s_eb2[v] : 0.0f;
#pragma unroll 3
    for (int uu = 0; uu < 17; ++uu) {
        const float* wr = &s_w1[(ub + uu) * 36];
        float h0 = s_eb1[ub + uu], h1 = 0.f, h2 = 0.f, h3 = 0.f;
#pragma unroll
        for (int c = 0; c < 16; c += 4) {
            h0 = fmaf(fi[c + 0], wr[c + 0], h0);
            h1 = fmaf(fi[c + 1], wr[c + 1], h1);
            h2 = fmaf(fi[c + 2], wr[c + 2], h2);
            h3 = fmaf(fi[c + 3], wr[c + 3], h3);
        }
#pragma unroll
        for (int c = 0; c < 16; c += 4) {
            h0 = fmaf(fj[c + 0], wr[16 + c + 0], h0);
            h1 = fmaf(fj[c + 1], wr[16 + c + 1], h1);
            h2 = fmaf(fj[c + 2], wr[16 + c + 2], h2);
            h3 = fmaf(fj[c + 3], wr[16 + c + 3], h3);
        }
        h0 = fmaf(rd, wr[32], h0);
        const float hh = silu_f((h0 + h1) + (h2 + h3));
        const float* w2r = &s_w2e[(ub + uu) * 16];
#pragma unroll
        for (int v = 0; v < 16; ++v) macc[v] = fmaf(hh, w2r[v], macc[v]);
    }

    // ---- combine 4 partials: qt1->A, qt3->B; qt0+=A, qt2+=B; qt2->B; qt0+=B, silu -> A ----
    if (qt == 1) {
#pragma unroll
        for (int v = 0; v < 16; ++v) s_bufA[g][v][lane] = macc[v];
    } else if (qt == 3) {
#pragma unroll
        for (int v = 0; v < 16; ++v) s_bufB[g][v][lane] = macc[v];
    }
    __syncthreads();   // sync1
    if (qt == 0) {
#pragma unroll
        for (int v = 0; v < 16; ++v) macc[v] += s_bufA[g][v][lane];
    } else if (qt == 2) {
#pragma unroll
        for (int v = 0; v < 16; ++v) { macc[v] += s_bufB[g][v][lane]; s_bufB[g][v][lane] = macc[v]; }
    }
    __syncthreads();   // sync2
    float mm[16];
    if (qt == 0) {
#pragma unroll
        for (int v = 0; v < 16; ++v) { macc[v] += s_bufB[g][v][lane]; mm[v] = silu_f(macc[v]); s_bufA[g][v][lane] = mm[v]; }
    }
    __syncthreads();   // sync3: mm ready
    if (qt != 0) {
#pragma unroll
        for (int v = 0; v < 16; ++v) mm[v] = s_bufA[g][v][lane];
    }

    // ---- specialization ----
    float mi_[16];
    if (qt == 1 || qt == 2) {
        // coors MLP half: t in [ (qt-1)*32, +32 )
        const int tb = (qt - 1) * 32;
        float wa = 0.f;
#pragma unroll 4
        for (int tt = 0; tt < 32; ++tt) {
            const float* cr = &s_cw1[(tb + tt) * 16];
            float a0 = s_cb1[tb + tt], a1 = 0.f;
#pragma unroll
            for (int v = 0; v < 16; v += 2) {
                a0 = fmaf(mm[v], cr[v], a0);
                a1 = fmaf(mm[v + 1], cr[v + 1], a1);
            }
            wa = fmaf(silu_f(a0 + a1), s_cw2v[tb + tt], wa);
        }
        if (qt == 1) s_wA[g][lane] = wa; else s_wB[g][lane] = wa;
    } else if (qt == 0) {
        // masked m_i over the node's 8 edges (lanes k=0..7 of each octet)
#pragma unroll
        for (int v = 0; v < 16; ++v) mi_[v] = em ? mm[v] : 0.f;
#pragma unroll
        for (int s = 1; s < 8; s <<= 1) {
#pragma unroll
            for (int v = 0; v < 16; ++v) mi_[v] += __shfl_xor(mi_[v], s, 64);
        }
    }
    __syncthreads();   // sync4: wa halves ready

    if (qt == 3) {
        const float we = em ? (s_wA[g][lane] + s_wB[g][lane] + s_cb2v) : 0.f;
        float wr0 = we * rel[0], wr1 = we * rel[1], wr2 = we * rel[2];
#pragma unroll
        for (int s = 1; s < 8; s <<= 1) {
            wr0 += __shfl_xor(wr0, s, 64);
            wr1 += __shfl_xor(wr1, s, 64);
            wr2 += __shfl_xor(wr2, s, 64);
        }
        if (k == 0) {
            coordsOut[(size_t)n * 3 + 0] = ci[0] + wr0;
            coordsOut[(size_t)n * 3 + 1] = ci[1] + wr1;
            coordsOut[(size_t)n * 3 + 2] = ci[2] + wr2;
        }
    } else if (qt == 0) {
        // ---- LayerNorm(fi) ----
        float mu = 0.f;
#pragma unroll
        for (int c = 0; c < 16; ++c) mu += fi[c];
        mu *= 0.0625f;
        float var = 0.f;
#pragma unroll
        for (int c = 0; c < 16; ++c) { const float dd = fi[c] - mu; var = fmaf(dd, dd, var); }
        var *= 0.0625f;
        const float rs = rsqrtf(var + LN_EPS);
        float nn[16];
#pragma unroll
        for (int c = 0; c < 16; ++c) nn[c] = fmaf((fi[c] - mu) * rs, s_lng[c], s_lnb[c]);

        // node MLP hidden: lane k owns units k*4..k*4+3
        float nh[4];
#pragma unroll
        for (int qq = 0; qq < 4; ++qq) {
            const int u = k * 4 + qq;
            const float* nr = &s_nw1[u * 36];
            float a0 = s_nb1[u], a1 = 0.f;
#pragma unroll
            for (int c = 0; c < 16; c += 2) {
                a0 = fmaf(nn[c], nr[c], a0);
                a1 = fmaf(nn[c + 1], nr[c + 1], a1);
            }
#pragma unroll
            for (int v = 0; v < 16; v += 2) {
                a0 = fmaf(mi_[v], nr[16 + v], a0);
                a1 = fmaf(mi_[v + 1], nr[16 + v + 1], a1);
            }
            nh[qq] = silu_f(a0 + a1);
        }
        // node MLP out: lane k computes channels 2k, 2k+1 via shfl gather
        const int c0 = 2 * k, c1 = 2 * k + 1;
        const float* w2a = &s_nw2[c0 * 36];
        const float* w2b = &s_nw2[c1 * 36];
        float o0 = s_nb2[c0], o1 = s_nb2[c1];
        const int lbase = lane & ~7;
#pragma unroll
        for (int u = 0; u < 32; ++u) {
            const float v = __shfl(nh[u & 3], lbase + (u >> 2), 64);
            o0 = fmaf(v, w2a[u], o0);
            o1 = fmaf(v, w2b[u], o1);
        }
        ((float2*)featsOut)[(size_t)n * 8 + k] = make_float2(fi[c0] + o0, fi[c1] + o1);
    }
}

// ---------------- final projection ----------------
__global__ __launch_bounds__(256) void final_kernel(
    const float* __restrict__ feats, const float* __restrict__ fw,
    const float* __restrict__ fb, float* __restrict__ out)
{
    const int nid = blockIdx.x * 256 + threadIdx.x;
    if (nid >= NB * SL) return;
    float f[DIM];
#pragma unroll
    for (int c = 0; c < DIM; ++c) f[c] = feats[nid * DIM + c];
#pragma unroll
    for (int o = 0; o < 3; ++o) {
        float acc = fb[o];
#pragma unroll
        for (int c = 0; c < DIM; ++c) acc = fmaf(f[c], fw[c * 3 + o], acc);
        out[nid * 3 + o] = acc;
    }
}

extern "C" void kernel_launch(void* const* d_in, const int* in_sizes, int n_in,
                              void* d_out, int out_size, void* d_ws, size_t ws_size,
                              hipStream_t stream) {
    const float* coords    = (const float*)d_in[0];
    const int*   residues  = (const int*)d_in[1];
    const int*   lengths   = (const int*)d_in[2];
    const float* token_emb = (const float*)d_in[3];
    const float* pos_emb   = (const float*)d_in[4];
    const float* ew1 = (const float*)d_in[5];
    const float* eb1 = (const float*)d_in[6];
    const float* ew2 = (const float*)d_in[7];
    const float* eb2 = (const float*)d_in[8];
    const float* cw1 = (const float*)d_in[9];
    const float* cb1 = (const float*)d_in[10];
    const float* cw2 = (const float*)d_in[11];
    const float* cb2 = (const float*)d_in[12];
    const float* lng = (const float*)d_in[13];
    const float* lnb = (const float*)d_in[14];
    const float* nw1 = (const float*)d_in[15];
    const float* nb1 = (const float*)d_in[16];
    const float* nw2 = (const float*)d_in[17];
    const float* nb2 = (const float*)d_in[18];
    const float* fw  = (const float*)d_in[19];
    const float* fb  = (const float*)d_in[20];

    float* ws = (float*)d_ws;
    float* coordsA = ws;
    float* coordsB = coordsA + NB * SL * 3;
    float* featsA  = coordsB + NB * SL * 3;
    float* featsB  = featsA + NB * SL * DIM;
    int*   idxbuf  = (int*)(featsB + NB * SL * DIM);
    float* w1t  = (float*)(idxbuf + NB * SL * KNN);
    float* cw1t = w1t + 3 * EH * W1T_STRIDE;
    float* nw1t = cw1t + 3 * CH * 16;
    float* nw2t = nw1t + 3 * NHID * 32;

    pack_kernel<<<32, 256, 0, stream>>>(ew1, cw1, nw1, nw2, w1t, cw1t, nw1t, nw2t);
    init_kernel<<<NB * SL / 256, 256, 0, stream>>>(coords, residues, token_emb, pos_emb, coordsA, featsA);

    float* cIn = coordsA; float* cOut = coordsB;
    float* fIn = featsA;  float* fOut = featsB;
    for (int d = 0; d < 3; ++d) {
        knn_kernel<<<NB * 32, 1024, 0, stream>>>(cIn, lengths, idxbuf);
        layer_kernel<<<NB * SL * KNN / 128, 512, 0, stream>>>(d, cIn, cOut, fIn, fOut, idxbuf, lengths,
            w1t, eb1, ew2, eb2, cw1t, cb1, cw2, cb2, lng, lnb, nw1t, nb1, nw2t, nb2);
        float* t;
        t = cIn; cIn = cOut; cOut = t;
        t = fIn; fIn = fOut; fOut = t;
    }

    final_kernel<<<NB * SL / 256, 256, 0, stream>>>(fIn, fw, fb, (float*)d_out);
}

// Round 6
// 321.752 us; speedup vs baseline: 1.0662x; 1.0662x over previous
//
#include <hip/hip_runtime.h>
#include <math.h>

typedef unsigned long long u64;
typedef unsigned int u32;

#define NB 16
#define SL 1024
#define DIM 16
#define MDIM 16
#define KNN 8
#define EH 66    /* edge hidden */
#define EHP 68   /* padded to 4*17 */
#define CH 64    /* coors hidden */
#define NHID 32  /* node hidden */
#define LN_EPS 1e-5f
#define W1T_STRIDE 36

__device__ __forceinline__ float silu_f(float x) {
    return x / (1.0f + __expf(-x));
}

// ---------------- init ----------------
__global__ __launch_bounds__(256) void init_kernel(
    const float* __restrict__ coords, const int* __restrict__ residues,
    const float* __restrict__ token_emb, const float* __restrict__ pos_emb,
    float* __restrict__ coordsA, float* __restrict__ featsA)
{
    const int nid = blockIdx.x * 256 + threadIdx.x;
    if (nid >= NB * SL) return;
    const int l = nid & (SL - 1);
    const int r = residues[nid];
#pragma unroll
    for (int c = 0; c < DIM; ++c)
        featsA[nid * DIM + c] = token_emb[r * DIM + c] + pos_emb[l * DIM + c];
#pragma unroll
    for (int c = 0; c < 3; ++c)
        coordsA[nid * 3 + c] = coords[nid * 3 + c];
}

// ---------------- weight transpose/pack ----------------
__global__ __launch_bounds__(256) void pack_kernel(
    const float* __restrict__ ew1, const float* __restrict__ cw1,
    const float* __restrict__ nw1, const float* __restrict__ nw2,
    float* __restrict__ w1t, float* __restrict__ cw1t,
    float* __restrict__ nw1t, float* __restrict__ nw2t)
{
    const int stride = gridDim.x * 256;
    const int t0 = blockIdx.x * 256 + threadIdx.x;
    for (int idx = t0; idx < 3 * EH * 33; idx += stride) {
        int d = idx / (EH * 33); int r = idx - d * EH * 33; int u = r / 33; int c = r - u * 33;
        w1t[(d * EH + u) * W1T_STRIDE + c] = ew1[(d * 33 + c) * EH + u];
    }
    for (int idx = t0; idx < 3 * CH * 16; idx += stride) {
        int d = idx / (CH * 16); int r = idx - d * CH * 16; int t = r >> 4; int v = r & 15;
        cw1t[(d * CH + t) * 16 + v] = cw1[(d * 16 + v) * CH + t];
    }
    for (int idx = t0; idx < 3 * NHID * 32; idx += stride) {
        int d = idx / (NHID * 32); int r = idx - d * NHID * 32; int u = r >> 5; int c = r & 31;
        nw1t[(d * NHID + u) * 32 + c] = nw1[(d * 32 + c) * NHID + u];
    }
    for (int idx = t0; idx < 3 * 16 * 32; idx += stride) {
        int d = idx / (16 * 32); int r = idx - d * 16 * 32; int c = r >> 5; int u = r & 31;
        nw2t[(d * 16 + c) * 32 + u] = nw2[(d * 32 + u) * 16 + c];
    }
}

// ---------------- kNN: float4 LDS staging, dual-stream insertion ----------------
__device__ __forceinline__ void merge8(u32* a, const u32* bb) {
    u32 c[8];
#pragma unroll
    for (int t = 0; t < 8; ++t) c[t] = min(a[t], bb[7 - t]);
#define MCAS(x, y) { u32 mn = min(c[x], c[y]); u32 mx = max(c[x], c[y]); c[x] = mn; c[y] = mx; }
    MCAS(0, 4) MCAS(1, 5) MCAS(2, 6) MCAS(3, 7)
    MCAS(0, 2) MCAS(1, 3) MCAS(4, 6) MCAS(5, 7)
    MCAS(0, 1) MCAS(2, 3) MCAS(4, 5) MCAS(6, 7)
#undef MCAS
#pragma unroll
    for (int t = 0; t < 8; ++t) a[t] = c[t];
}

__device__ __forceinline__ void knn_step(
    const float4* s_cand4, int j, int i, int len,
    float xi, float yi, float zi, u32* lst)
{
    const float4 cj = s_cand4[j];
    const float dx = xi - cj.x, dy = yi - cj.y, dz = zi - cj.z;
    const float dist = dx * dx + dy * dy + dz * dz;
    const bool valid = j < len;
    // order-preserving pack; dist >= 0 so transform = set sign, truncate low 10 bits
    const u32 kd = (__float_as_uint(dist) | 0x80000000u) & 0xFFFFFC00u;
    u32 key = valid ? kd : 0xC7C35000u;                             // key(1e5f)
    if (valid && (j == i + 1 || j + 1 == i)) key = 0x80000000u;     // key(0.0f) adjacency
    if (j == i) key = 0x407FFC00u;                                  // key(-1.0f) self
    key |= (u32)j;
#pragma unroll
    for (int p = 7; p >= 1; --p)
        lst[p] = (key < lst[p]) ? ((key < lst[p - 1]) ? lst[p - 1] : key) : lst[p];
    lst[0] = min(key, lst[0]);
}

__global__ __launch_bounds__(1024) void knn_kernel(
    const float* __restrict__ coords, const int* __restrict__ lengths,
    int* __restrict__ idxbuf)
{
    __shared__ float4 s_cand4[SL];        // 16 KB
    __shared__ u32 lists[32][32][9];      // 36 KB
    const int tid = threadIdx.x;
    const int b = blockIdx.x >> 5;
    const int i0 = (blockIdx.x & 31) << 5;
    const int len = lengths[b];
    const float* cb = coords + (size_t)b * SL * 3;
    for (int idx = tid; idx < SL; idx += 1024)
        s_cand4[idx] = make_float4(cb[idx * 3 + 0], cb[idx * 3 + 1], cb[idx * 3 + 2], 0.0f);
    __syncthreads();

    const int wv = tid >> 6;
    const int lane = tid & 63;
    const int q = lane & 31;
    const int sub = lane >> 5;
    const int s = wv * 2 + sub;          // slice 0..31
    const int i = i0 + q;
    const float4 ciq = s_cand4[i];
    const float xi = ciq.x, yi = ciq.y, zi = ciq.z;

    u32 l0[8], l1[8];
#pragma unroll
    for (int t = 0; t < 8; ++t) { l0[t] = 0xFFFFFFFFu; l1[t] = 0xFFFFFFFFu; }

    const int jbase = s << 5;
#pragma unroll 4
    for (int jj = 0; jj < 32; jj += 2) {
        knn_step(s_cand4, jbase + jj,     i, len, xi, yi, zi, l0);
        knn_step(s_cand4, jbase + jj + 1, i, len, xi, yi, zi, l1);
    }
    merge8(l0, l1);

#pragma unroll
    for (int t = 0; t < 8; ++t) lists[s][q][t] = l0[t];
    __syncthreads();

    if (tid < 512) {
        const int p = tid >> 5, qq = tid & 31;
        u32 a[8], bb[8];
#pragma unroll
        for (int t = 0; t < 8; ++t) { a[t] = lists[2 * p][qq][t]; bb[t] = lists[2 * p + 1][qq][t]; }
        merge8(a, bb);
#pragma unroll
        for (int t = 0; t < 8; ++t) lists[2 * p][qq][t] = a[t];
    }
    __syncthreads();
    if (tid < 256) {
        const int p = tid >> 5, qq = tid & 31;
        u32 a[8], bb[8];
#pragma unroll
        for (int t = 0; t < 8; ++t) { a[t] = lists[4 * p][qq][t]; bb[t] = lists[4 * p + 2][qq][t]; }
        merge8(a, bb);
#pragma unroll
        for (int t = 0; t < 8; ++t) lists[4 * p][qq][t] = a[t];
    }
    __syncthreads();
    if (tid < 128) {
        const int p = tid >> 5, qq = tid & 31;
        u32 a[8], bb[8];
#pragma unroll
        for (int t = 0; t < 8; ++t) { a[t] = lists[8 * p][qq][t]; bb[t] = lists[8 * p + 4][qq][t]; }
        merge8(a, bb);
#pragma unroll
        for (int t = 0; t < 8; ++t) lists[8 * p][qq][t] = a[t];
    }
    __syncthreads();
    if (tid < 64) {
        const int p = tid >> 5, qq = tid & 31;
        u32 a[8], bb[8];
#pragma unroll
        for (int t = 0; t < 8; ++t) { a[t] = lists[16 * p][qq][t]; bb[t] = lists[16 * p + 8][qq][t]; }
        merge8(a, bb);
#pragma unroll
        for (int t = 0; t < 8; ++t) lists[16 * p][qq][t] = a[t];
    }
    __syncthreads();
    if (tid < 32) {
        const int qq = tid;
        u32 a[8], bb[8];
#pragma unroll
        for (int t = 0; t < 8; ++t) { a[t] = lists[0][qq][t]; bb[t] = lists[16][qq][t]; }
        merge8(a, bb);
        const size_t node = (size_t)b * SL + i0 + qq;
        int4 r0 = make_int4((int)(a[0] & 1023u), (int)(a[1] & 1023u), (int)(a[2] & 1023u), (int)(a[3] & 1023u));
        int4 r1 = make_int4((int)(a[4] & 1023u), (int)(a[5] & 1023u), (int)(a[6] & 1023u), (int)(a[7] & 1023u));
        ((int4*)idxbuf)[node * 2 + 0] = r0;
        ((int4*)idxbuf)[node * 2 + 1] = r1;
    }
}

// ---------------- EGNN layer: 256 thr = 64 edges x 4 quarter-waves,
// LDS-broadcast weights, wave specialization. (256,5): VGPR cap 102 -> no spill ----------------
__global__ __launch_bounds__(256, 5) void layer_kernel(
    const int d,
    const float* __restrict__ coordsIn, float* __restrict__ coordsOut,
    const float* __restrict__ featsIn, float* __restrict__ featsOut,
    const int* __restrict__ idxbuf, const int* __restrict__ lengths,
    const float* __restrict__ w1t, const float* __restrict__ g_eb1,
    const float* __restrict__ g_ew2, const float* __restrict__ g_eb2,
    const float* __restrict__ cw1t, const float* __restrict__ g_cb1,
    const float* __restrict__ g_cw2, const float* __restrict__ g_cb2,
    const float* __restrict__ g_lng, const float* __restrict__ g_lnb,
    const float* __restrict__ nw1t, const float* __restrict__ g_nb1,
    const float* __restrict__ nw2t, const float* __restrict__ g_nb2)
{
    __shared__ float s_w1[EHP * 36];      // rows 66,67 zero
    __shared__ float s_w2e[EHP * 16];     // rows 66,67 zero
    __shared__ float s_cw1[CH * 16];
    __shared__ float s_cw2v[CH];
    __shared__ float s_nw1[NHID * 36];
    __shared__ float s_nw2[16 * 36];
    __shared__ float s_eb1[EHP], s_eb2[16], s_cb1[CH];
    __shared__ float s_lng[16], s_lnb[16], s_nb1[32], s_nb2[16];
    __shared__ float s_cb2v;
    __shared__ float s_bufA[16][66];      // exchange, [v][lane]
    __shared__ float s_bufB[16][66];
    __shared__ float s_wA[64], s_wB[64];

    const int tid = threadIdx.x;
    for (int t = tid; t < EHP * 36; t += 256) s_w1[t] = (t < EH * 36) ? w1t[d * EH * 36 + t] : 0.0f;
    for (int t = tid; t < EHP * 16; t += 256) s_w2e[t] = (t < EH * 16) ? g_ew2[d * EH * 16 + t] : 0.0f;
    for (int t = tid; t < CH * 16; t += 256) s_cw1[t] = cw1t[d * CH * 16 + t];
    for (int t = tid; t < NHID * 32; t += 256) s_nw1[(t >> 5) * 36 + (t & 31)] = nw1t[d * NHID * 32 + t];
    for (int t = tid; t < 16 * 32; t += 256) s_nw2[(t >> 5) * 36 + (t & 31)] = nw2t[d * 16 * 32 + t];
    if (tid < CH) { s_cw2v[tid] = g_cw2[d * CH + tid]; s_cb1[tid] = g_cb1[d * CH + tid]; }
    if (tid < EHP) s_eb1[tid] = (tid < EH) ? g_eb1[d * EH + tid] : 0.0f;
    if (tid >= 128 && tid < 144) {
        const int c = tid - 128;
        s_eb2[c] = g_eb2[d * 16 + c];
        s_lng[c] = g_lng[d * 16 + c];
        s_lnb[c] = g_lnb[d * 16 + c];
        s_nb2[c] = g_nb2[d * 16 + c];
    }
    if (tid >= 160 && tid < 192) s_nb1[tid - 160] = g_nb1[d * 32 + (tid - 160)];
    if (tid == 200) s_cb2v = g_cb2[d];

    const int qt = tid >> 6;         // quarter (wave-uniform)
    const int lane = tid & 63;
    const int e = blockIdx.x * 64 + lane;
    const int n = e >> 3;
    const int b = n >> 10;
    const int i = n & (SL - 1);
    const int k = lane & 7;
    const int len = lengths[b];
    const int j = idxbuf[e];
    const bool em = (i < len) && (j < len);

    // ---- inputs ----
    float fi[16], fj[16];
    {
        const float4* pp = (const float4*)(featsIn + (size_t)n * DIM);
        float4 a = pp[0], c2 = pp[1], c3 = pp[2], c4 = pp[3];
        fi[0]=a.x; fi[1]=a.y; fi[2]=a.z; fi[3]=a.w;
        fi[4]=c2.x; fi[5]=c2.y; fi[6]=c2.z; fi[7]=c2.w;
        fi[8]=c3.x; fi[9]=c3.y; fi[10]=c3.z; fi[11]=c3.w;
        fi[12]=c4.x; fi[13]=c4.y; fi[14]=c4.z; fi[15]=c4.w;
    }
    {
        const float4* pp = (const float4*)(featsIn + ((size_t)b * SL + j) * DIM);
        float4 a = pp[0], c2 = pp[1], c3 = pp[2], c4 = pp[3];
        fj[0]=a.x; fj[1]=a.y; fj[2]=a.z; fj[3]=a.w;
        fj[4]=c2.x; fj[5]=c2.y; fj[6]=c2.z; fj[7]=c2.w;
        fj[8]=c3.x; fj[9]=c3.y; fj[10]=c3.z; fj[11]=c3.w;
        fj[12]=c4.x; fj[13]=c4.y; fj[14]=c4.z; fj[15]=c4.w;
    }
    float ci[3], rel[3];
    {
        const float* cp = coordsIn + (size_t)n * 3;
        const float* cq = coordsIn + ((size_t)b * SL + j) * 3;
        ci[0] = cp[0]; ci[1] = cp[1]; ci[2] = cp[2];
        rel[0] = ci[0] - cq[0]; rel[1] = ci[1] - cq[1]; rel[2] = ci[2] - cq[2];
    }
    const float rd = fmaf(rel[0], rel[0], fmaf(rel[1], rel[1], rel[2] * rel[2]));

    __syncthreads();   // sync0: weights staged

    // ---- edge MLP quarter: units [qt*17, qt*17+17) (rows 66,67 zero) ----
    const int ub = qt * 17;
    float macc[16];
#pragma unroll
    for (int v = 0; v < 16; ++v) macc[v] = (qt == 0) ? s_eb2[v] : 0.0f;
#pragma unroll 3
    for (int uu = 0; uu < 17; ++uu) {
        const float* wr = &s_w1[(ub + uu) * 36];
        float h0 = s_eb1[ub + uu], h1 = 0.f, h2 = 0.f, h3 = 0.f;
#pragma unroll
        for (int c = 0; c < 16; c += 4) {
            h0 = fmaf(fi[c + 0], wr[c + 0], h0);
            h1 = fmaf(fi[c + 1], wr[c + 1], h1);
            h2 = fmaf(fi[c + 2], wr[c + 2], h2);
            h3 = fmaf(fi[c + 3], wr[c + 3], h3);
        }
#pragma unroll
        for (int c = 0; c < 16; c += 4) {
            h0 = fmaf(fj[c + 0], wr[16 + c + 0], h0);
            h1 = fmaf(fj[c + 1], wr[16 + c + 1], h1);
            h2 = fmaf(fj[c + 2], wr[16 + c + 2], h2);
            h3 = fmaf(fj[c + 3], wr[16 + c + 3], h3);
        }
        h0 = fmaf(rd, wr[32], h0);
        const float hh = silu_f((h0 + h1) + (h2 + h3));
        const float* w2r = &s_w2e[(ub + uu) * 16];
#pragma unroll
        for (int v = 0; v < 16; ++v) macc[v] = fmaf(hh, w2r[v], macc[v]);
    }

    // ---- combine 4 partials ----
    if (qt == 1) {
#pragma unroll
        for (int v = 0; v < 16; ++v) s_bufA[v][lane] = macc[v];
    } else if (qt == 3) {
#pragma unroll
        for (int v = 0; v < 16; ++v) s_bufB[v][lane] = macc[v];
    }
    __syncthreads();   // sync1
    if (qt == 0) {
#pragma unroll
        for (int v = 0; v < 16; ++v) macc[v] += s_bufA[v][lane];
    } else if (qt == 2) {
#pragma unroll
        for (int v = 0; v < 16; ++v) { macc[v] += s_bufB[v][lane]; s_bufB[v][lane] = macc[v]; }
    }
    __syncthreads();   // sync2
    float mm[16];
    if (qt == 0) {
#pragma unroll
        for (int v = 0; v < 16; ++v) { macc[v] += s_bufB[v][lane]; mm[v] = silu_f(macc[v]); s_bufA[v][lane] = mm[v]; }
    }
    __syncthreads();   // sync3: mm ready
    if (qt != 0) {
#pragma unroll
        for (int v = 0; v < 16; ++v) mm[v] = s_bufA[v][lane];
    }

    // ---- specialization ----
    float mi_[16];
    if (qt == 1 || qt == 2) {
        const int tb = (qt - 1) * 32;
        float wa = 0.f;
#pragma unroll 4
        for (int tt = 0; tt < 32; ++tt) {
            const float* cr = &s_cw1[(tb + tt) * 16];
            float a0 = s_cb1[tb + tt], a1 = 0.f;
#pragma unroll
            for (int v = 0; v < 16; v += 2) {
                a0 = fmaf(mm[v], cr[v], a0);
                a1 = fmaf(mm[v + 1], cr[v + 1], a1);
            }
            wa = fmaf(silu_f(a0 + a1), s_cw2v[tb + tt], wa);
        }
        if (qt == 1) s_wA[lane] = wa; else s_wB[lane] = wa;
    } else if (qt == 0) {
#pragma unroll
        for (int v = 0; v < 16; ++v) mi_[v] = em ? mm[v] : 0.f;
#pragma unroll
        for (int s = 1; s < 8; s <<= 1) {
#pragma unroll
            for (int v = 0; v < 16; ++v) mi_[v] += __shfl_xor(mi_[v], s, 64);
        }
    }
    __syncthreads();   // sync4: wa halves ready

    if (qt == 3) {
        const float we = em ? (s_wA[lane] + s_wB[lane] + s_cb2v) : 0.f;
        float wr0 = we * rel[0], wr1 = we * rel[1], wr2 = we * rel[2];
#pragma unroll
        for (int s = 1; s < 8; s <<= 1) {
            wr0 += __shfl_xor(wr0, s, 64);
            wr1 += __shfl_xor(wr1, s, 64);
            wr2 += __shfl_xor(wr2, s, 64);
        }
        if (k == 0) {
            coordsOut[(size_t)n * 3 + 0] = ci[0] + wr0;
            coordsOut[(size_t)n * 3 + 1] = ci[1] + wr1;
            coordsOut[(size_t)n * 3 + 2] = ci[2] + wr2;
        }
    } else if (qt == 0) {
        // LayerNorm(fi)
        float mu = 0.f;
#pragma unroll
        for (int c = 0; c < 16; ++c) mu += fi[c];
        mu *= 0.0625f;
        float var = 0.f;
#pragma unroll
        for (int c = 0; c < 16; ++c) { const float dd = fi[c] - mu; var = fmaf(dd, dd, var); }
        var *= 0.0625f;
        const float rs = rsqrtf(var + LN_EPS);
        float nn[16];
#pragma unroll
        for (int c = 0; c < 16; ++c) nn[c] = fmaf((fi[c] - mu) * rs, s_lng[c], s_lnb[c]);

        // node MLP hidden: lane k owns units k*4..k*4+3
        float nh[4];
#pragma unroll
        for (int qq = 0; qq < 4; ++qq) {
            const int u = k * 4 + qq;
            const float* nr = &s_nw1[u * 36];
            float a0 = s_nb1[u], a1 = 0.f;
#pragma unroll
            for (int c = 0; c < 16; c += 2) {
                a0 = fmaf(nn[c], nr[c], a0);
                a1 = fmaf(nn[c + 1], nr[c + 1], a1);
            }
#pragma unroll
            for (int v = 0; v < 16; v += 2) {
                a0 = fmaf(mi_[v], nr[16 + v], a0);
                a1 = fmaf(mi_[v + 1], nr[16 + v + 1], a1);
            }
            nh[qq] = silu_f(a0 + a1);
        }
        // node MLP out: lane k computes channels 2k, 2k+1 via shfl gather
        const int c0 = 2 * k, c1 = 2 * k + 1;
        const float* w2a = &s_nw2[c0 * 36];
        const float* w2b = &s_nw2[c1 * 36];
        float o0 = s_nb2[c0], o1 = s_nb2[c1];
        const int lbase = lane & ~7;
#pragma unroll
        for (int u = 0; u < 32; ++u) {
            const float v = __shfl(nh[u & 3], lbase + (u >> 2), 64);
            o0 = fmaf(v, w2a[u], o0);
            o1 = fmaf(v, w2b[u], o1);
        }
        ((float2*)featsOut)[(size_t)n * 8 + k] = make_float2(fi[c0] + o0, fi[c1] + o1);
    }
}

// ---------------- final projection ----------------
__global__ __launch_bounds__(256) void final_kernel(
    const float* __restrict__ feats, const float* __restrict__ fw,
    const float* __restrict__ fb, float* __restrict__ out)
{
    const int nid = blockIdx.x * 256 + threadIdx.x;
    if (nid >= NB * SL) return;
    float f[DIM];
#pragma unroll
    for (int c = 0; c < DIM; ++c) f[c] = feats[nid * DIM + c];
#pragma unroll
    for (int o = 0; o < 3; ++o) {
        float acc = fb[o];
#pragma unroll
        for (int c = 0; c < DIM; ++c) acc = fmaf(f[c], fw[c * 3 + o], acc);
        out[nid * 3 + o] = acc;
    }
}

extern "C" void kernel_launch(void* const* d_in, const int* in_sizes, int n_in,
                              void* d_out, int out_size, void* d_ws, size_t ws_size,
                              hipStream_t stream) {
    const float* coords    = (const float*)d_in[0];
    const int*   residues  = (const int*)d_in[1];
    const int*   lengths   = (const int*)d_in[2];
    const float* token_emb = (const float*)d_in[3];
    const float* pos_emb   = (const float*)d_in[4];
    const float* ew1 = (const float*)d_in[5];
    const float* eb1 = (const float*)d_in[6];
    const float* ew2 = (const float*)d_in[7];
    const float* eb2 = (const float*)d_in[8];
    const float* cw1 = (const float*)d_in[9];
    const float* cb1 = (const float*)d_in[10];
    const float* cw2 = (const float*)d_in[11];
    const float* cb2 = (const float*)d_in[12];
    const float* lng = (const float*)d_in[13];
    const float* lnb = (const float*)d_in[14];
    const float* nw1 = (const float*)d_in[15];
    const float* nb1 = (const float*)d_in[16];
    const float* nw2 = (const float*)d_in[17];
    const float* nb2 = (const float*)d_in[18];
    const float* fw  = (const float*)d_in[19];
    const float* fb  = (const float*)d_in[20];

    float* ws = (float*)d_ws;
    float* coordsA = ws;
    float* coordsB = coordsA + NB * SL * 3;
    float* featsA  = coordsB + NB * SL * 3;
    float* featsB  = featsA + NB * SL * DIM;
    int*   idxbuf  = (int*)(featsB + NB * SL * DIM);
    float* w1t  = (float*)(idxbuf + NB * SL * KNN);
    float* cw1t = w1t + 3 * EH * W1T_STRIDE;
    float* nw1t = cw1t + 3 * CH * 16;
    float* nw2t = nw1t + 3 * NHID * 32;

    pack_kernel<<<32, 256, 0, stream>>>(ew1, cw1, nw1, nw2, w1t, cw1t, nw1t, nw2t);
    init_kernel<<<NB * SL / 256, 256, 0, stream>>>(coords, residues, token_emb, pos_emb, coordsA, featsA);

    float* cIn = coordsA; float* cOut = coordsB;
    float* fIn = featsA;  float* fOut = featsB;
    for (int d = 0; d < 3; ++d) {
        knn_kernel<<<NB * 32, 1024, 0, stream>>>(cIn, lengths, idxbuf);
        layer_kernel<<<NB * SL * KNN / 64, 256, 0, stream>>>(d, cIn, cOut, fIn, fOut, idxbuf, lengths,
            w1t, eb1, ew2, eb2, cw1t, cb1, cw2, cb2, lng, lnb, nw1t, nb1, nw2t, nb2);
        float* t;
        t = cIn; cIn = cOut; cOut = t;
        t = fIn; fIn = fOut; fOut = t;
    }

    final_kernel<<<NB * SL / 256, 256, 0, stream>>>(fIn, fw, fb, (float*)d_out);
}

// Round 8
// 307.640 us; speedup vs baseline: 1.1151x; 1.0459x over previous
//
#include <hip/hip_runtime.h>
#include <math.h>

typedef unsigned long long u64;
typedef unsigned int u32;

#define NB 16
#define SL 1024
#define DIM 16
#define MDIM 16
#define KNN 8
#define EH 66    /* edge hidden */
#define CH 64    /* coors hidden */
#define NHID 32  /* node hidden */
#define LN_EPS 1e-5f
#define W1T_STRIDE 36
#define ABSTRIDE 72   /* A/B table: per node 2 halves of 36 (33 used) */

__device__ __forceinline__ float silu_f(float x) {
    return x / (1.0f + __expf(-x));
}

// ---------------- init ----------------
__global__ __launch_bounds__(256) void init_kernel(
    const float* __restrict__ coords, const int* __restrict__ residues,
    const float* __restrict__ token_emb, const float* __restrict__ pos_emb,
    float* __restrict__ coordsA, float* __restrict__ featsA)
{
    const int nid = blockIdx.x * 256 + threadIdx.x;
    if (nid >= NB * SL) return;
    const int l = nid & (SL - 1);
    const int r = residues[nid];
#pragma unroll
    for (int c = 0; c < DIM; ++c)
        featsA[nid * DIM + c] = token_emb[r * DIM + c] + pos_emb[l * DIM + c];
#pragma unroll
    for (int c = 0; c < 3; ++c)
        coordsA[nid * 3 + c] = coords[nid * 3 + c];
}

// ---------------- weight transpose/pack ----------------
__global__ __launch_bounds__(256) void pack_kernel(
    const float* __restrict__ ew1, const float* __restrict__ cw1,
    const float* __restrict__ nw1, const float* __restrict__ nw2,
    float* __restrict__ w1t, float* __restrict__ cw1t,
    float* __restrict__ nw1t, float* __restrict__ nw2t)
{
    const int stride = gridDim.x * 256;
    const int t0 = blockIdx.x * 256 + threadIdx.x;
    for (int idx = t0; idx < 3 * EH * 33; idx += stride) {
        int d = idx / (EH * 33); int r = idx - d * EH * 33; int u = r / 33; int c = r - u * 33;
        w1t[(d * EH + u) * W1T_STRIDE + c] = ew1[(d * 33 + c) * EH + u];
    }
    for (int idx = t0; idx < 3 * CH * 16; idx += stride) {
        int d = idx / (CH * 16); int r = idx - d * CH * 16; int t = r >> 4; int v = r & 15;
        cw1t[(d * CH + t) * 16 + v] = cw1[(d * 16 + v) * CH + t];
    }
    for (int idx = t0; idx < 3 * NHID * 32; idx += stride) {
        int d = idx / (NHID * 32); int r = idx - d * NHID * 32; int u = r >> 5; int c = r & 31;
        nw1t[(d * NHID + u) * 32 + c] = nw1[(d * 32 + c) * NHID + u];
    }
    for (int idx = t0; idx < 3 * 16 * 32; idx += stride) {
        int d = idx / (16 * 32); int r = idx - d * 16 * 32; int c = r >> 5; int u = r & 31;
        nw2t[(d * 16 + c) * 32 + u] = nw2[(d * 32 + u) * 16 + c];
    }
}

// ---------------- per-node edge-MLP1 precompute: A_n = W1a f_n + b1, B_n = W1b f_n ----------------
__global__ __launch_bounds__(256) void nodepre_kernel(
    const int d, const float* __restrict__ featsIn,
    const float* __restrict__ w1t, const float* __restrict__ g_eb1,
    float* __restrict__ Atab, float* __restrict__ Btab)
{
    __shared__ float s_w1[EH * W1T_STRIDE];
    __shared__ float s_eb1[EH];
    const int tid = threadIdx.x;
    for (int t = tid; t < EH * W1T_STRIDE; t += 256) s_w1[t] = w1t[d * EH * W1T_STRIDE + t];
    if (tid < EH) s_eb1[tid] = g_eb1[d * EH + tid];
    __syncthreads();

    const int t0 = blockIdx.x * 256 + tid;   // 0..32767
    const int n = t0 >> 1;
    const int h = t0 & 1;
    float f[16];
    {
        const float4* pp = (const float4*)(featsIn + (size_t)n * DIM);
        float4 a = pp[0], c2 = pp[1], c3 = pp[2], c4 = pp[3];
        f[0]=a.x; f[1]=a.y; f[2]=a.z; f[3]=a.w;
        f[4]=c2.x; f[5]=c2.y; f[6]=c2.z; f[7]=c2.w;
        f[8]=c3.x; f[9]=c3.y; f[10]=c3.z; f[11]=c3.w;
        f[12]=c4.x; f[13]=c4.y; f[14]=c4.z; f[15]=c4.w;
    }
    const int ub = h * 33;
    float* Ao = Atab + (size_t)n * ABSTRIDE + 36 * h;
    float* Bo = Btab + (size_t)n * ABSTRIDE + 36 * h;
#pragma unroll 3
    for (int t = 0; t < 33; ++t) {
        const float* wr = &s_w1[(ub + t) * W1T_STRIDE];
        float a0 = s_eb1[ub + t], a1 = 0.f, b0 = 0.f, b1 = 0.f;
#pragma unroll
        for (int c = 0; c < 16; c += 2) {
            a0 = fmaf(f[c],     wr[c],          a0);
            a1 = fmaf(f[c + 1], wr[c + 1],      a1);
            b0 = fmaf(f[c],     wr[16 + c],     b0);
            b1 = fmaf(f[c + 1], wr[16 + c + 1], b1);
        }
        Ao[t] = a0 + a1;
        Bo[t] = b0 + b1;
    }
}

// ---------------- kNN: wave-per-query, LDS-staged candidates, in-wave butterfly merge ----------------
#define CSU(x, y) { u32 mn = min(lst[x], lst[y]); u32 mx = max(lst[x], lst[y]); lst[x] = mn; lst[y] = mx; }

__global__ __launch_bounds__(1024) void knn_kernel(
    const float* __restrict__ coords, const int* __restrict__ lengths,
    int* __restrict__ idxbuf)
{
    __shared__ float4 s_cand4[SL];        // 16 KB
    const int tid = threadIdx.x;
    const int b = blockIdx.x >> 6;
    const int i0 = (blockIdx.x & 63) << 4;
    const int len = lengths[b];
    const float* cb = coords + (size_t)b * SL * 3;
    {
        const int idx = tid;   // exactly one per thread
        s_cand4[idx] = make_float4(cb[idx * 3 + 0], cb[idx * 3 + 1], cb[idx * 3 + 2], 0.0f);
    }
    __syncthreads();

    const int wv = tid >> 6;
    const int lane = tid & 63;
    const int i = i0 + wv;               // this wave's query (wave-uniform)
    const float4 ciq = s_cand4[i];
    const float xi = ciq.x, yi = ciq.y, zi = ciq.z;

    u32 lst[8];
#pragma unroll
    for (int t = 0; t < 8; ++t) lst[t] = 0xFFFFFFFFu;

#pragma unroll 4
    for (int t = 0; t < 16; ++t) {
        const int j = t * 64 + lane;
        const float4 cj = s_cand4[j];
        const float dx = xi - cj.x, dy = yi - cj.y, dz = zi - cj.z;
        const float dist = dx * dx + dy * dy + dz * dz;
        const bool valid = j < len;
        const u32 kd = (__float_as_uint(dist) | 0x80000000u) & 0xFFFFFC00u;
        u32 key = valid ? kd : 0xC7C35000u;                           // key(1e5f)
        if (valid && (j == i + 1 || j + 1 == i)) key = 0x80000000u;   // key(0.0f) adjacency
        if (j == i) key = 0x407FFC00u;                                // key(-1.0f) self
        key |= (u32)j;
#pragma unroll
        for (int p = 7; p >= 1; --p)
            lst[p] = (key < lst[p]) ? ((key < lst[p - 1]) ? lst[p - 1] : key) : lst[p];
        lst[0] = min(key, lst[0]);
    }

    // butterfly merge across 64 lanes
#pragma unroll
    for (int m = 1; m < 64; m <<= 1) {
        u32 o[8];
#pragma unroll
        for (int t = 0; t < 8; ++t) o[t] = (u32)__shfl_xor((int)lst[7 - t], m, 64);
#pragma unroll
        for (int t = 0; t < 8; ++t) lst[t] = min(lst[t], o[t]);
        CSU(0, 4) CSU(1, 5) CSU(2, 6) CSU(3, 7)
        CSU(0, 2) CSU(1, 3) CSU(4, 6) CSU(5, 7)
        CSU(0, 1) CSU(2, 3) CSU(4, 5) CSU(6, 7)
    }

    if (lane == 0) {
        const size_t node = (size_t)b * SL + i;
        int4 r0 = make_int4((int)(lst[0] & 1023u), (int)(lst[1] & 1023u), (int)(lst[2] & 1023u), (int)(lst[3] & 1023u));
        int4 r1 = make_int4((int)(lst[4] & 1023u), (int)(lst[5] & 1023u), (int)(lst[6] & 1023u), (int)(lst[7] & 1023u));
        ((int4*)idxbuf)[node * 2 + 0] = r0;
        ((int4*)idxbuf)[node * 2 + 1] = r1;
    }
}

// ---------------- EGNN layer: thread=edge, 2-way wave split, A/B-factored edge MLP ----------------
__global__ __launch_bounds__(256, 5) void layer_kernel(
    const int d,
    const float* __restrict__ coordsIn, float* __restrict__ coordsOut,
    const float* __restrict__ featsIn, float* __restrict__ featsOut,
    const int* __restrict__ idxbuf, const int* __restrict__ lengths,
    const float* __restrict__ Atab, const float* __restrict__ Btab,
    const float* __restrict__ w1t,
    const float* __restrict__ g_ew2, const float* __restrict__ g_eb2,
    const float* __restrict__ cw1t, const float* __restrict__ g_cb1,
    const float* __restrict__ g_cw2, const float* __restrict__ g_cb2,
    const float* __restrict__ g_lng, const float* __restrict__ g_lnb,
    const float* __restrict__ nw1t, const float* __restrict__ g_nb1,
    const float* __restrict__ nw2t, const float* __restrict__ g_nb2)
{
    __shared__ float s_w2e[EH * 16];      // 4224 B
    __shared__ float s_w1c[EH];           // rd column of W1
    __shared__ float s_cw1[CH * 16];
    __shared__ float s_cw2v[CH];
    __shared__ float s_cb1[CH];
    __shared__ float s_nw1[NHID * 36];
    __shared__ float s_nw2[16 * 36];
    __shared__ float s_eb2[16];
    __shared__ float s_lng[16], s_lnb[16], s_nb1[32], s_nb2[16];
    __shared__ float s_cb2v;
    __shared__ float s_buf[2][16][66];    // macc/mm exchange [g][v][lane]
    __shared__ float s_wx[2][2][64];      // coors partials [g][h][lane]

    const int tid = threadIdx.x;
    for (int t = tid; t < EH * 16; t += 256) s_w2e[t] = g_ew2[d * EH * 16 + t];
    for (int t = tid; t < CH * 16; t += 256) s_cw1[t] = cw1t[d * CH * 16 + t];
    for (int t = tid; t < NHID * 32; t += 256) s_nw1[(t >> 5) * 36 + (t & 31)] = nw1t[d * NHID * 32 + t];
    for (int t = tid; t < 16 * 32; t += 256) s_nw2[(t >> 5) * 36 + (t & 31)] = nw2t[d * 16 * 32 + t];
    if (tid < CH) { s_cw2v[tid] = g_cw2[d * CH + tid]; s_cb1[tid] = g_cb1[d * CH + tid]; }
    if (tid < EH) s_w1c[tid] = w1t[d * EH * W1T_STRIDE + tid * W1T_STRIDE + 32];
    if (tid >= 128 && tid < 144) {
        const int c = tid - 128;
        s_eb2[c] = g_eb2[d * 16 + c];
        s_lng[c] = g_lng[d * 16 + c];
        s_lnb[c] = g_lnb[d * 16 + c];
        s_nb2[c] = g_nb2[d * 16 + c];
    }
    if (tid >= 160 && tid < 192) s_nb1[tid - 160] = g_nb1[d * 32 + (tid - 160)];
    if (tid == 200) s_cb2v = g_cb2[d];

    const int wv = tid >> 6;
    const int g = wv >> 1;           // edge group (64 edges)
    const int h = wv & 1;            // half (wave-uniform)
    const int lane = tid & 63;
    const int e = blockIdx.x * 128 + g * 64 + lane;
    const int n = e >> 3;
    const int b = n >> 10;
    const int i = n & (SL - 1);
    const int k = lane & 7;
    const int len = lengths[b];
    const int j = idxbuf[e];
    const bool em = (i < len) && (j < len);

    // coords / rel / rd
    float ci[3], rel[3];
    {
        const float* cp = coordsIn + (size_t)n * 3;
        const float* cq = coordsIn + ((size_t)b * SL + j) * 3;
        ci[0] = cp[0]; ci[1] = cp[1]; ci[2] = cp[2];
        rel[0] = ci[0] - cq[0]; rel[1] = ci[1] - cq[1]; rel[2] = ci[2] - cq[2];
    }
    const float rd = fmaf(rel[0], rel[0], fmaf(rel[1], rel[1], rel[2] * rel[2]));

    // fi only needed by h==1 (LN + node MLP + residual)
    float fi[16];
    if (h) {
        const float4* pp = (const float4*)(featsIn + (size_t)n * DIM);
        float4 a = pp[0], c2 = pp[1], c3 = pp[2], c4 = pp[3];
        fi[0]=a.x; fi[1]=a.y; fi[2]=a.z; fi[3]=a.w;
        fi[4]=c2.x; fi[5]=c2.y; fi[6]=c2.z; fi[7]=c2.w;
        fi[8]=c3.x; fi[9]=c3.y; fi[10]=c3.z; fi[11]=c3.w;
        fi[12]=c4.x; fi[13]=c4.y; fi[14]=c4.z; fi[15]=c4.w;
    }

    const float4* Aq = (const float4*)(Atab + (size_t)n * ABSTRIDE + 36 * h);
    // FIX (r7 bug): Btab is indexed by GLOBAL node id — j is within-batch
    const float4* Bq = (const float4*)(Btab + ((size_t)b * SL + j) * ABSTRIDE + 36 * h);

    __syncthreads();   // sync0: weights staged

    // ---- edge MLP half: units [h*33, h*33+33), h_u = A_i[u] + B_j[u] + rd*w1c[u] ----
    const int ub = h * 33;
    float macc[16];
#pragma unroll
    for (int v = 0; v < 16; ++v) macc[v] = h ? 0.0f : s_eb2[v];
#pragma unroll
    for (int c = 0; c < 9; ++c) {
        const float4 a4 = Aq[c];
        const float4 b4 = Bq[c];
        const float av[4] = {a4.x, a4.y, a4.z, a4.w};
        const float bv[4] = {b4.x, b4.y, b4.z, b4.w};
#pragma unroll
        for (int q = 0; q < 4; ++q) {
            const int t = 4 * c + q;
            if (t < 33) {
                const float hin = fmaf(rd, s_w1c[ub + t], av[q] + bv[q]);
                const float hh = silu_f(hin);
                const float* w2r = &s_w2e[(ub + t) * 16];
#pragma unroll
                for (int v = 0; v < 16; ++v) macc[v] = fmaf(hh, w2r[v], macc[v]);
            }
        }
    }

    // ---- combine halves: h1 -> buf; h0 adds, silu -> mm -> buf; h1 reads ----
    if (h) {
#pragma unroll
        for (int v = 0; v < 16; ++v) s_buf[g][v][lane] = macc[v];
    }
    __syncthreads();   // sync1
    float mm[16];
    if (!h) {
#pragma unroll
        for (int v = 0; v < 16; ++v) { macc[v] += s_buf[g][v][lane]; mm[v] = silu_f(macc[v]); s_buf[g][v][lane] = mm[v]; }
    }
    __syncthreads();   // sync2
    if (h) {
#pragma unroll
        for (int v = 0; v < 16; ++v) mm[v] = s_buf[g][v][lane];
    }

    // ---- coors MLP half: rows [h*32, h*32+32) ----
    {
        const int tb = h * 32;
        float wa = 0.f;
#pragma unroll 4
        for (int tt = 0; tt < 32; ++tt) {
            const float* cr = &s_cw1[(tb + tt) * 16];
            float a0 = s_cb1[tb + tt], a1 = 0.f;
#pragma unroll
            for (int v = 0; v < 16; v += 2) {
                a0 = fmaf(mm[v], cr[v], a0);
                a1 = fmaf(mm[v + 1], cr[v + 1], a1);
            }
            wa = fmaf(silu_f(a0 + a1), s_cw2v[tb + tt], wa);
        }
        s_wx[g][h][lane] = wa;
    }
    __syncthreads();   // sync3

    if (!h) {
        // ---- coordinate update ----
        const float we = em ? (s_wx[g][0][lane] + s_wx[g][1][lane] + s_cb2v) : 0.f;
        float wr0 = we * rel[0], wr1 = we * rel[1], wr2 = we * rel[2];
#pragma unroll
        for (int s = 1; s < 8; s <<= 1) {
            wr0 += __shfl_xor(wr0, s, 64);
            wr1 += __shfl_xor(wr1, s, 64);
            wr2 += __shfl_xor(wr2, s, 64);
        }
        if (k == 0) {
            coordsOut[(size_t)n * 3 + 0] = ci[0] + wr0;
            coordsOut[(size_t)n * 3 + 1] = ci[1] + wr1;
            coordsOut[(size_t)n * 3 + 2] = ci[2] + wr2;
        }
    } else {
        // ---- m_i (masked sum over octet) ----
        float mi_[16];
#pragma unroll
        for (int v = 0; v < 16; ++v) mi_[v] = em ? mm[v] : 0.f;
#pragma unroll
        for (int s = 1; s < 8; s <<= 1) {
#pragma unroll
            for (int v = 0; v < 16; ++v) mi_[v] += __shfl_xor(mi_[v], s, 64);
        }
        // ---- LayerNorm(fi) ----
        float mu = 0.f;
#pragma unroll
        for (int c = 0; c < 16; ++c) mu += fi[c];
        mu *= 0.0625f;
        float var = 0.f;
#pragma unroll
        for (int c = 0; c < 16; ++c) { const float dd = fi[c] - mu; var = fmaf(dd, dd, var); }
        var *= 0.0625f;
        const float rs = rsqrtf(var + LN_EPS);
        float nn[16];
#pragma unroll
        for (int c = 0; c < 16; ++c) nn[c] = fmaf((fi[c] - mu) * rs, s_lng[c], s_lnb[c]);

        // node MLP hidden: lane k owns units 4k..4k+3
        float nh[4];
#pragma unroll
        for (int qq = 0; qq < 4; ++qq) {
            const int u = k * 4 + qq;
            const float* nr = &s_nw1[u * 36];
            float a0 = s_nb1[u], a1 = 0.f;
#pragma unroll
            for (int c = 0; c < 16; c += 2) {
                a0 = fmaf(nn[c], nr[c], a0);
                a1 = fmaf(nn[c + 1], nr[c + 1], a1);
            }
#pragma unroll
            for (int v = 0; v < 16; v += 2) {
                a0 = fmaf(mi_[v], nr[16 + v], a0);
                a1 = fmaf(mi_[v + 1], nr[16 + v + 1], a1);
            }
            nh[qq] = silu_f(a0 + a1);
        }
        // node MLP out: lane k computes channels 2k, 2k+1 via shfl gather over octet
        const int c0 = 2 * k, c1 = 2 * k + 1;
        const float* w2a = &s_nw2[c0 * 36];
        const float* w2b = &s_nw2[c1 * 36];
        float o0 = s_nb2[c0], o1 = s_nb2[c1];
        const int lbase = lane & ~7;
#pragma unroll
        for (int u = 0; u < 32; ++u) {
            const float v = __shfl(nh[u & 3], lbase + (u >> 2), 64);
            o0 = fmaf(v, w2a[u], o0);
            o1 = fmaf(v, w2b[u], o1);
        }
        ((float2*)featsOut)[(size_t)n * 8 + k] = make_float2(fi[c0] + o0, fi[c1] + o1);
    }
}

// ---------------- final projection ----------------
__global__ __launch_bounds__(256) void final_kernel(
    const float* __restrict__ feats, const float* __restrict__ fw,
    const float* __restrict__ fb, float* __restrict__ out)
{
    const int nid = blockIdx.x * 256 + threadIdx.x;
    if (nid >= NB * SL) return;
    float f[DIM];
#pragma unroll
    for (int c = 0; c < DIM; ++c) f[c] = feats[nid * DIM + c];
#pragma unroll
    for (int o = 0; o < 3; ++o) {
        float acc = fb[o];
#pragma unroll
        for (int c = 0; c < DIM; ++c) acc = fmaf(f[c], fw[c * 3 + o], acc);
        out[nid * 3 + o] = acc;
    }
}

extern "C" void kernel_launch(void* const* d_in, const int* in_sizes, int n_in,
                              void* d_out, int out_size, void* d_ws, size_t ws_size,
                              hipStream_t stream) {
    const float* coords    = (const float*)d_in[0];
    const int*   residues  = (const int*)d_in[1];
    const int*   lengths   = (const int*)d_in[2];
    const float* token_emb = (const float*)d_in[3];
    const float* pos_emb   = (const float*)d_in[4];
    const float* ew1 = (const float*)d_in[5];
    const float* eb1 = (const float*)d_in[6];
    const float* ew2 = (const float*)d_in[7];
    const float* eb2 = (const float*)d_in[8];
    const float* cw1 = (const float*)d_in[9];
    const float* cb1 = (const float*)d_in[10];
    const float* cw2 = (const float*)d_in[11];
    const float* cb2 = (const float*)d_in[12];
    const float* lng = (const float*)d_in[13];
    const float* lnb = (const float*)d_in[14];
    const float* nw1 = (const float*)d_in[15];
    const float* nb1 = (const float*)d_in[16];
    const float* nw2 = (const float*)d_in[17];
    const float* nb2 = (const float*)d_in[18];
    const float* fw  = (const float*)d_in[19];
    const float* fb  = (const float*)d_in[20];

    float* ws = (float*)d_ws;
    float* coordsA = ws;                               // 49152
    float* coordsB = coordsA + NB * SL * 3;            // 49152
    float* featsA  = coordsB + NB * SL * 3;            // 262144
    float* featsB  = featsA + NB * SL * DIM;           // 262144
    int*   idxbuf  = (int*)(featsB + NB * SL * DIM);   // 131072 ints
    float* w1t  = (float*)(idxbuf + NB * SL * KNN);    // 7128
    float* cw1t = w1t + 3 * EH * W1T_STRIDE;           // 3072
    float* nw1t = cw1t + 3 * CH * 16;                  // 3072
    float* nw2t = nw1t + 3 * NHID * 32;                // 1536
    float* Atab = nw2t + 3 * 16 * 32;                  // 16384*72 = 1179648
    float* Btab = Atab + (size_t)NB * SL * ABSTRIDE;   // 1179648

    pack_kernel<<<32, 256, 0, stream>>>(ew1, cw1, nw1, nw2, w1t, cw1t, nw1t, nw2t);
    init_kernel<<<NB * SL / 256, 256, 0, stream>>>(coords, residues, token_emb, pos_emb, coordsA, featsA);

    float* cIn = coordsA; float* cOut = coordsB;
    float* fIn = featsA;  float* fOut = featsB;
    for (int d = 0; d < 3; ++d) {
        knn_kernel<<<NB * 64, 1024, 0, stream>>>(cIn, lengths, idxbuf);
        nodepre_kernel<<<NB * SL * 2 / 256, 256, 0, stream>>>(d, fIn, w1t, eb1, Atab, Btab);
        layer_kernel<<<NB * SL * KNN / 128, 256, 0, stream>>>(d, cIn, cOut, fIn, fOut, idxbuf, lengths,
            Atab, Btab, w1t, ew2, eb2, cw1t, cb1, cw2, cb2, lng, lnb, nw1t, nb1, nw2t, nb2);
        float* t;
        t = cIn; cIn = cOut; cOut = t;
        t = fIn; fIn = fOut; fOut = t;
    }

    final_kernel<<<NB * SL / 256, 256, 0, stream>>>(fIn, fw, fb, (float*)d_out);
}